// Round 7
// baseline (1879.160 us; speedup 1.0000x reference)
//
#include <hip/hip_runtime.h>
#include <hip/hip_bf16.h>

typedef __hip_bfloat16 bf16;
typedef unsigned short u16;
typedef unsigned int u32;

__device__ __forceinline__ float b2f(bf16 v) { return __bfloat162float(v); }
__device__ __forceinline__ bf16  f2b(float v) { return __float2bfloat16(v); }
__device__ __forceinline__ float us2f(u16 u) { return __uint_as_float((u32)u << 16); }
__device__ __forceinline__ u16   f2us(float v) { bf16 b = __float2bfloat16(v); return *(u16*)&b; }
__device__ __forceinline__ float ulo(u32 u)  { return __uint_as_float(u << 16); }
__device__ __forceinline__ float uhi(u32 u)  { return __uint_as_float(u & 0xFFFF0000u); }

// ---------------------------------------------------------------------------
// Static device arena (BSS, ~143 MB): converted inputs + weights + scratch.
// ---------------------------------------------------------------------------
#define OFF_IMGS 0
#define OFF_C24  12441600
#define OFF_C48  15980544
#define OFF_WTS  19519488
#define OFF_A    20119488
#define OFF_B    54819488
#define ARENA_N  71319488L

__device__ bf16 g_arena[ARENA_N];
__device__ int  g_isf32;

// ---------------------------------------------------------------------------
// Dtype detection (bf16 N(0,1) never has exponent >= 0x8D; fp32 misread does).
// ---------------------------------------------------------------------------
__global__ void detect_kern(const void* imgs)
{
    if (threadIdx.x != 0) return;
    const u16* u = (const u16*)imgs;
    int f32 = 0;
    for (int i = 0; i < 256; ++i) {
        int e = (u[i] >> 7) & 0xFF;
        if (e >= 0x8D) f32 = 1;
    }
    g_isf32 = f32;
}

__global__ void convert_kern(const void* __restrict__ src, int dst_off, int n)
{
    int i = blockIdx.x * blockDim.x + threadIdx.x;
    if (i >= n) return;
    float v = g_isf32 ? ((const float*)src)[i] : b2f(((const bf16*)src)[i]);
    g_arena[(long)dst_off + i] = f2b(v);
}

struct CvtEnt { const void* src; int dst_off; int n; };
struct CvtTab { CvtEnt e[50]; };
__global__ void convert_many_kern(CvtTab tab)
{
    CvtEnt ent = tab.e[blockIdx.y];
    int i = blockIdx.x * blockDim.x + threadIdx.x;
    if (i >= ent.n) return;
    float v = g_isf32 ? ((const float*)ent.src)[i] : b2f(((const bf16*)ent.src)[i]);
    g_arena[(long)ent.dst_off + i] = f2b(v);
}

__device__ __forceinline__ void stout(void* base, long idx, float v, int f32)
{
    if (f32) ((float*)base)[idx] = v;
    else     ((bf16*)base)[idx] = f2b(v);
}

// ---------------------------------------------------------------------------
// Generic LDS-resident conv for crop nets (whole image fits in LDS).
// ---------------------------------------------------------------------------
template<int CIN,int KH,int KW,int H,int W,int OH,int OW,int CO,int OBLK,int R>
__launch_bounds__(256)
__global__ void conv_a_kern(int in_off, int w_off, int b_off, int a_off, int out_off)
{
    constexpr int KTOT = CIN * KH * KW;
    constexpr int INCNT = CIN * H * W;
    constexpr int OPT = OBLK / 8;
    constexpr int NPX = OH * OW;
    __shared__ __align__(16) u16 in_s[INCNT];
    __shared__ __align__(16) u16 w_s[KTOT * OBLK];

    int n = blockIdx.x, pxc = blockIdx.y, oc = blockIdx.z;
    const u16* ga = (const u16*)g_arena;

    const u32* src = (const u32*)(ga + in_off + (long)n * INCNT);
    u32* dst = (u32*)in_s;
    for (int i = threadIdx.x; i < INCNT / 2; i += 256) dst[i] = src[i];
    for (int i = threadIdx.x; i < KTOT * OBLK; i += 256) {
        int o_l = i % OBLK, k = i / OBLK;
        int o = oc * OBLK + o_l;
        w_s[i] = (o < CO) ? ga[w_off + (long)o * KTOT + k] : (u16)0;
    }
    __syncthreads();

    int lane = threadIdx.x & 31, og = threadIdx.x >> 5;
    int pixoff[R], pxg[R];
    bool vld[R];
    #pragma unroll
    for (int r = 0; r < R; ++r) {
        int px = pxc * (32 * R) + lane + r * 32;
        vld[r] = px < NPX;
        int p = vld[r] ? px : 0;
        pxg[r] = p;
        pixoff[r] = (p / OW) * W + (p % OW);
    }
    float acc[R][OPT];
    #pragma unroll
    for (int r = 0; r < R; ++r)
        #pragma unroll
        for (int j = 0; j < OPT; ++j) acc[r][j] = 0.f;

    const u32* wu = (const u32*)w_s;
    for (int c = 0; c < CIN; ++c) {
        #pragma unroll
        for (int ky = 0; ky < KH; ++ky) {
            #pragma unroll
            for (int kx = 0; kx < KW; ++kx) {
                int k = (c * KH + ky) * KW + kx;
                int ub = c * (H * W) + ky * W + kx;
                float a[R];
                #pragma unroll
                for (int r = 0; r < R; ++r) a[r] = us2f(in_s[ub + pixoff[r]]);
                int wb = (k * OBLK + og * OPT) >> 1;
                float wv[OPT];
                #pragma unroll
                for (int jj = 0; jj < OPT / 2; ++jj) {
                    u32 u = wu[wb + jj];
                    wv[2 * jj] = ulo(u); wv[2 * jj + 1] = uhi(u);
                }
                #pragma unroll
                for (int r = 0; r < R; ++r)
                    #pragma unroll
                    for (int j = 0; j < OPT; ++j)
                        acc[r][j] += a[r] * wv[j];
            }
        }
    }
    #pragma unroll
    for (int j = 0; j < OPT; ++j) {
        int o = oc * OBLK + og * OPT + j;
        if (o < CO) {
            float b = us2f(ga[b_off + o]);
            float al = us2f(ga[a_off + o]);
            #pragma unroll
            for (int r = 0; r < R; ++r) if (vld[r]) {
                float v = acc[r][j] + b;
                v = v > 0.f ? v : v * al;
                g_arena[(long)out_off + ((long)n * CO + o) * NPX + pxg[r]] = f2b(v);
            }
        }
    }
}

// ---------------------------------------------------------------------------
// PNet conv1 (3->10) + PReLU + maxpool 2x2 s2.
// ---------------------------------------------------------------------------
__launch_bounds__(256)
__global__ void pnet_c1p_kern(int w_off, int b_off, int a_off, int out_off)
{
    __shared__ u16 patch[3 * 34 * 34];
    __shared__ __align__(16) u16 w_s[27 * 16];
    int n = blockIdx.x, pty = blockIdx.y, ptx = blockIdx.z;
    int cy0 = pty * 32, cx0 = ptx * 32;
    const u16* ga = (const u16*)g_arena;

    for (int i = threadIdx.x; i < 3468; i += 256) {
        int c = i / 1156, rem = i % 1156, py = rem / 34, pxx = rem % 34;
        int iy = cy0 + py, ix = cx0 + pxx;
        u16 v = 0;
        if (iy < 720 && ix < 720)
            v = ga[OFF_IMGS + ((long)(n * 3 + c) * 720 + iy) * 720 + ix];
        patch[i] = v;
    }
    for (int i = threadIdx.x; i < 27 * 16; i += 256) {
        int o = i % 16, k = i / 16;
        w_s[i] = (o < 10) ? ga[w_off + o * 27 + k] : (u16)0;
    }
    __syncthreads();

    int px = threadIdx.x % 16, py = threadIdx.x / 16;
    float acc[2][2][10];
    #pragma unroll
    for (int a = 0; a < 2; ++a)
        #pragma unroll
        for (int b = 0; b < 2; ++b)
            #pragma unroll
            for (int o = 0; o < 10; ++o) acc[a][b][o] = 0.f;

    const uint4* wq = (const uint4*)w_s;
    for (int c = 0; c < 3; ++c) {
        #pragma unroll
        for (int ky = 0; ky < 3; ++ky) {
            #pragma unroll
            for (int kx = 0; kx < 3; ++kx) {
                int k = (c * 3 + ky) * 3 + kx;
                float a[2][2];
                #pragma unroll
                for (int dy = 0; dy < 2; ++dy)
                    #pragma unroll
                    for (int dx = 0; dx < 2; ++dx)
                        a[dy][dx] = us2f(patch[c * 1156 + (2 * py + dy + ky) * 34 + (2 * px + dx + kx)]);
                uint4 q0 = wq[k * 2], q1 = wq[k * 2 + 1];
                float wv[10];
                wv[0] = ulo(q0.x); wv[1] = uhi(q0.x); wv[2] = ulo(q0.y); wv[3] = uhi(q0.y);
                wv[4] = ulo(q0.z); wv[5] = uhi(q0.z); wv[6] = ulo(q0.w); wv[7] = uhi(q0.w);
                wv[8] = ulo(q1.x); wv[9] = uhi(q1.x);
                #pragma unroll
                for (int o = 0; o < 10; ++o)
                    #pragma unroll
                    for (int dy = 0; dy < 2; ++dy)
                        #pragma unroll
                        for (int dx = 0; dx < 2; ++dx)
                            acc[dy][dx][o] += a[dy][dx] * wv[o];
            }
        }
    }
    int pgy = pty * 16 + py, pgx = ptx * 16 + px;
    if (pgy < 359 && pgx < 359) {
        #pragma unroll
        for (int o = 0; o < 10; ++o) {
            float b = us2f(ga[b_off + o]);
            float al = us2f(ga[a_off + o]);
            float m = -1e30f;
            #pragma unroll
            for (int dy = 0; dy < 2; ++dy)
                #pragma unroll
                for (int dx = 0; dx < 2; ++dx) {
                    float v = acc[dy][dx][o] + b;
                    v = v > 0.f ? v : v * al;
                    m = fmaxf(m, v);
                }
            g_arena[(long)out_off + ((long)(n * 10 + o) * 359 + pgy) * 359 + pgx] = f2b(m);
        }
    }
}

// ---------------------------------------------------------------------------
// PNet conv2 (10->16).
// ---------------------------------------------------------------------------
__launch_bounds__(256)
__global__ void pnet_c2_kern(int in_off, int w_off, int b_off, int a_off, int out_off)
{
    __shared__ u16 patch[10 * 34 * 34];
    __shared__ __align__(16) u16 w_s[90 * 16];
    int n = blockIdx.x, ty = blockIdx.y, tx = blockIdx.z;
    int y0 = ty * 32, x0 = tx * 32;
    const u16* ga = (const u16*)g_arena;

    for (int i = threadIdx.x; i < 11560; i += 256) {
        int c = i / 1156, rem = i % 1156, py = rem / 34, pxx = rem % 34;
        int iy = y0 + py, ix = x0 + pxx;
        u16 v = 0;
        if (iy < 359 && ix < 359)
            v = ga[in_off + ((long)(n * 10 + c) * 359 + iy) * 359 + ix];
        patch[i] = v;
    }
    for (int i = threadIdx.x; i < 1440; i += 256) {
        int o = i % 16, k = i / 16;
        w_s[i] = ga[w_off + o * 90 + k];
    }
    __syncthreads();

    int x = threadIdx.x % 32, yg = threadIdx.x / 32;
    float acc[4][16];
    #pragma unroll
    for (int r = 0; r < 4; ++r)
        #pragma unroll
        for (int o = 0; o < 16; ++o) acc[r][o] = 0.f;

    const uint4* wq = (const uint4*)w_s;
    for (int c = 0; c < 10; ++c) {
        #pragma unroll
        for (int ky = 0; ky < 3; ++ky) {
            #pragma unroll
            for (int kx = 0; kx < 3; ++kx) {
                int k = (c * 3 + ky) * 3 + kx;
                float a[4];
                #pragma unroll
                for (int r = 0; r < 4; ++r)
                    a[r] = us2f(patch[c * 1156 + (yg + 8 * r + ky) * 34 + (x + kx)]);
                uint4 q0 = wq[k * 2], q1 = wq[k * 2 + 1];
                float wv[16];
                wv[0]=ulo(q0.x); wv[1]=uhi(q0.x); wv[2]=ulo(q0.y); wv[3]=uhi(q0.y);
                wv[4]=ulo(q0.z); wv[5]=uhi(q0.z); wv[6]=ulo(q0.w); wv[7]=uhi(q0.w);
                wv[8]=ulo(q1.x); wv[9]=uhi(q1.x); wv[10]=ulo(q1.y); wv[11]=uhi(q1.y);
                wv[12]=ulo(q1.z); wv[13]=uhi(q1.z); wv[14]=ulo(q1.w); wv[15]=uhi(q1.w);
                #pragma unroll
                for (int r = 0; r < 4; ++r)
                    #pragma unroll
                    for (int o = 0; o < 16; ++o)
                        acc[r][o] += a[r] * wv[o];
            }
        }
    }
    #pragma unroll
    for (int o = 0; o < 16; ++o) {
        float b = us2f(ga[b_off + o]);
        float al = us2f(ga[a_off + o]);
        #pragma unroll
        for (int r = 0; r < 4; ++r) {
            int gy = y0 + yg + 8 * r, gx = x0 + x;
            if (gy < 357 && gx < 357) {
                float v = acc[r][o] + b;
                v = v > 0.f ? v : v * al;
                g_arena[(long)out_off + ((long)(n * 16 + o) * 357 + gy) * 357 + gx] = f2b(v);
            }
        }
    }
}

// ---------------------------------------------------------------------------
// PNet conv3 (16->32) + PReLU + 1x1 heads + softmax, fused.
// c3s now bf16, TRANSPOSED [o][p] (stride 264): write phase (fixed o per
// wave, consecutive p) and read phase (fixed o per instr, consecutive p) are
// both conflict-free. LDS 55.3 -> 38.0 KB => 4 blocks/CU (was 2).
// ---------------------------------------------------------------------------
__launch_bounds__(256)
__global__ void pnet_c3h_kern(int in_off, int w3o, int b3o, int a3o,
                              int w41o, int b41o, int w42o, int b42o, void* dout)
{
    __shared__ u16 patch[16 * 10 * 34];
    __shared__ __align__(16) u16 w3s[144 * 32];
    __shared__ u16 c3s[32 * 264];
    __shared__ float b3f[32], a3f[32], w41f[64], w42f[128], b41f[2], b42f[4];

    int n = blockIdx.x, by = blockIdx.y, tx = blockIdx.z;
    int gy0 = by * 8, gx0 = tx * 32;
    const u16* ga = (const u16*)g_arena;

    for (int i = threadIdx.x; i < 5440; i += 256) {
        int c = i / 340, rem = i % 340, py = rem / 34, pxx = rem % 34;
        int iy = gy0 + py, ix = gx0 + pxx;
        u16 v = 0;
        if (iy < 357 && ix < 357)
            v = ga[in_off + ((long)(n * 16 + c) * 357 + iy) * 357 + ix];
        patch[i] = v;
    }
    for (int i = threadIdx.x; i < 4608; i += 256) {
        int o = i % 32, k = i / 32;
        w3s[i] = ga[w3o + o * 144 + k];
    }
    for (int i = threadIdx.x; i < 32; i += 256) { b3f[i] = us2f(ga[b3o + i]); a3f[i] = us2f(ga[a3o + i]); }
    for (int i = threadIdx.x; i < 64; i += 256) w41f[i] = us2f(ga[w41o + i]);
    for (int i = threadIdx.x; i < 128; i += 256) w42f[i] = us2f(ga[w42o + i]);
    if (threadIdx.x < 2) b41f[threadIdx.x] = us2f(ga[b41o + threadIdx.x]);
    if (threadIdx.x < 4) b42f[threadIdx.x] = us2f(ga[b42o + threadIdx.x]);
    __syncthreads();

    int lane = threadIdx.x & 63, og = threadIdx.x >> 6;
    int pb[4];
    #pragma unroll
    for (int r = 0; r < 4; ++r) {
        int p = lane + 64 * r;
        pb[r] = (p >> 5) * 34 + (p & 31);
    }
    float acc[4][8];
    #pragma unroll
    for (int r = 0; r < 4; ++r)
        #pragma unroll
        for (int j = 0; j < 8; ++j) acc[r][j] = 0.f;

    const uint4* wq = (const uint4*)w3s;
    for (int c = 0; c < 16; ++c) {
        #pragma unroll
        for (int ky = 0; ky < 3; ++ky) {
            #pragma unroll
            for (int kx = 0; kx < 3; ++kx) {
                int k = (c * 3 + ky) * 3 + kx;
                int ub = c * 340 + ky * 34 + kx;
                float a[4];
                #pragma unroll
                for (int r = 0; r < 4; ++r) a[r] = us2f(patch[ub + pb[r]]);
                uint4 q = wq[k * 4 + og];
                float wv[8];
                wv[0]=ulo(q.x); wv[1]=uhi(q.x); wv[2]=ulo(q.y); wv[3]=uhi(q.y);
                wv[4]=ulo(q.z); wv[5]=uhi(q.z); wv[6]=ulo(q.w); wv[7]=uhi(q.w);
                #pragma unroll
                for (int r = 0; r < 4; ++r)
                    #pragma unroll
                    for (int j = 0; j < 8; ++j)
                        acc[r][j] += a[r] * wv[j];
            }
        }
    }
    #pragma unroll
    for (int j = 0; j < 8; ++j) {
        int o = og * 8 + j;
        float b = b3f[o], al = a3f[o];
        #pragma unroll
        for (int r = 0; r < 4; ++r) {
            int p = lane + 64 * r;
            float v = acc[r][j] + b;
            v = v > 0.f ? v : v * al;
            c3s[o * 264 + p] = f2us(v);
        }
    }
    __syncthreads();

    int p = threadIdx.x;
    int gy = gy0 + (p >> 5), gx = gx0 + (p & 31);
    if (gy < 355 && gx < 355) {
        int f32 = g_isf32;
        float l0 = b41f[0], l1 = b41f[1];
        float r0 = b42f[0], r1 = b42f[1], r2 = b42f[2], r3 = b42f[3];
        #pragma unroll
        for (int o = 0; o < 32; ++o) {
            float v = us2f(c3s[o * 264 + p]);
            l0 += v * w41f[o];
            l1 += v * w41f[32 + o];
            r0 += v * w42f[o];
            r1 += v * w42f[32 + o];
            r2 += v * w42f[64 + o];
            r3 += v * w42f[96 + o];
        }
        float mx = fmaxf(l0, l1);
        float e0 = __expf(l0 - mx), e1 = __expf(l1 - mx);
        float inv = 1.f / (e0 + e1);
        const long HW = 355L * 355L;
        long pix = (long)gy * 355 + gx;
        stout(dout, 4032800 + ((long)n * 2 + 0) * HW + pix, e0 * inv, f32);
        stout(dout, 4032800 + ((long)n * 2 + 1) * HW + pix, e1 * inv, f32);
        stout(dout, ((long)n * 4 + 0) * HW + pix, r0, f32);
        stout(dout, ((long)n * 4 + 1) * HW + pix, r1, f32);
        stout(dout, ((long)n * 4 + 2) * HW + pix, r2, f32);
        stout(dout, ((long)n * 4 + 3) * HW + pix, r3, f32);
    }
}

// ---------------------------------------------------------------------------
// MaxPool2d, ceil_mode (OOB taps skipped).
// ---------------------------------------------------------------------------
__global__ void maxpool_kern(int in_off, int out_off,
                             int H, int W, int OH, int OW, int k, int s, int total)
{
    int tid = blockIdx.x * blockDim.x + threadIdx.x;
    if (tid >= total) return;
    int x = tid % OW;
    int t = tid / OW;
    int y = t % OH;
    int nc = t / OH;
    const bf16* ip = g_arena + in_off + (long)nc * H * W;
    int sy = y * s, sx = x * s;
    float m = -1e30f;
    for (int ky = 0; ky < k; ++ky) {
        int iy = sy + ky;
        if (iy >= H) break;
        for (int kx = 0; kx < k; ++kx) {
            int ix = sx + kx;
            if (ix >= W) break;
            m = fmaxf(m, b2f(ip[iy * W + ix]));
        }
    }
    g_arena[(long)out_off + tid] = f2b(m);
}

// ---------------------------------------------------------------------------
// Flatten: torch permute(0,3,2,1).view -> out[n][w*H*C + h*C + c]
// ---------------------------------------------------------------------------
__global__ void flatten_kern(int in_off, int out_off, int C, int H, int W, int total)
{
    int tid = blockIdx.x * blockDim.x + threadIdx.x;
    if (tid >= total) return;
    int CHW = C * H * W;
    int n = tid / CHW;
    int k = tid % CHW;
    int w = k / (H * C);
    int r = k % (H * C);
    int h = r / C;
    int c = r % C;
    g_arena[(long)out_off + tid] = g_arena[in_off + (((long)n * C + c) * H + h) * W + w];
}

// ---------------------------------------------------------------------------
// Dense + bias + PReLU as tiled LDS GEMM (32x32 tile, 2x2 micro-tile).
// ---------------------------------------------------------------------------
__launch_bounds__(256)
__global__ void dense_tile_kern(int in_off, int w_off, int b_off, int a_off, int out_off,
                                int K, int J)
{
    __shared__ u16 in_s[32 * 66];
    __shared__ u16 w_s[32 * 66];
    int n0 = blockIdx.x * 32, j0 = blockIdx.y * 32;
    const u16* ga = (const u16*)g_arena;
    const u16* fin = ga + in_off;
    const u16* wts = ga + w_off;
    int sy = threadIdx.x >> 4, sx = threadIdx.x & 15;

    float acc00 = 0.f, acc01 = 0.f, acc10 = 0.f, acc11 = 0.f;

    for (int kc = 0; kc < K; kc += 64) {
        #pragma unroll
        for (int it = 0; it < 4; ++it) {
            int i = threadIdx.x + it * 256;
            int row = i >> 5, c2 = i & 31;
            u32 v = *(const u32*)(fin + (long)(n0 + row) * K + kc + c2 * 2);
            *(u32*)&in_s[row * 66 + c2 * 2] = v;
            u32 wv = *(const u32*)(wts + (long)(j0 + row) * K + kc + c2 * 2);
            *(u32*)&w_s[row * 66 + c2 * 2] = wv;
        }
        __syncthreads();
        #pragma unroll
        for (int kk = 0; kk < 64; ++kk) {
            float a0 = us2f(in_s[(2 * sy) * 66 + kk]);
            float a1 = us2f(in_s[(2 * sy + 1) * 66 + kk]);
            float b0 = us2f(w_s[(2 * sx) * 66 + kk]);
            float b1 = us2f(w_s[(2 * sx + 1) * 66 + kk]);
            acc00 += a0 * b0; acc01 += a0 * b1;
            acc10 += a1 * b0; acc11 += a1 * b1;
        }
        __syncthreads();
    }

    float accs[2][2] = {{acc00, acc01}, {acc10, acc11}};
    #pragma unroll
    for (int jj = 0; jj < 2; ++jj) {
        int j = j0 + 2 * sx + jj;
        float b = us2f(ga[b_off + j]);
        float al = us2f(ga[a_off + j]);
        #pragma unroll
        for (int ss = 0; ss < 2; ++ss) {
            int n = n0 + 2 * sy + ss;
            float v = accs[ss][jj] + b;
            v = v > 0.f ? v : v * al;
            g_arena[(long)out_off + (long)n * J + j] = f2b(v);
        }
    }
}

// ---------------------------------------------------------------------------
// Heads, wave-per-sample: 64 lanes partition K; butterfly shuffle reduction.
// ---------------------------------------------------------------------------
template<int K, int J1, int J2>
__launch_bounds__(256)
__global__ void heads_wave_kern(int fc_off, int wSo, int bSo, int w1o, int b1o,
                                int w2o, int b2o, void* dout,
                                long outS_off, long out1_off, long out2_off, int N)
{
    constexpr int KPL = K / 64;
    constexpr int NACC = 2 + J1 + J2;
    int wave = (blockIdx.x * blockDim.x + threadIdx.x) >> 6;
    int lane = threadIdx.x & 63;
    if (wave >= N) return;
    const u16* ga = (const u16*)g_arena;
    const u16* f  = ga + fc_off + (long)wave * K;
    const u16* wS = ga + wSo;
    const u16* w1 = ga + w1o;
    const u16* w2 = ga + w2o;

    float acc[NACC];
    #pragma unroll
    for (int j = 0; j < NACC; ++j) acc[j] = 0.f;

    #pragma unroll
    for (int kk = 0; kk < KPL; ++kk) {
        int k = lane + kk * 64;
        float fv = us2f(f[k]);
        acc[0] += fv * us2f(wS[k]);
        acc[1] += fv * us2f(wS[K + k]);
        #pragma unroll
        for (int j = 0; j < J1; ++j)
            acc[2 + j] += fv * us2f(w1[j * K + k]);
        #pragma unroll
        for (int j = 0; j < J2; ++j)
            acc[2 + J1 + j] += fv * us2f(w2[j * K + k]);
    }
    #pragma unroll
    for (int j = 0; j < NACC; ++j)
        #pragma unroll
        for (int off = 32; off > 0; off >>= 1)
            acc[j] += __shfl_xor(acc[j], off, 64);

    if (lane == 0) {
        int f32 = g_isf32;
        float l0 = acc[0] + us2f(ga[bSo + 0]);
        float l1 = acc[1] + us2f(ga[bSo + 1]);
        float m = fmaxf(l0, l1);
        float e0 = __expf(l0 - m), e1 = __expf(l1 - m);
        float inv = 1.f / (e0 + e1);
        stout(dout, outS_off + (long)wave * 2 + 0, e0 * inv, f32);
        stout(dout, outS_off + (long)wave * 2 + 1, e1 * inv, f32);
        #pragma unroll
        for (int j = 0; j < J1; ++j)
            stout(dout, out1_off + (long)wave * J1 + j, acc[2 + j] + us2f(ga[b1o + j]), f32);
        #pragma unroll
        for (int j = 0; j < J2; ++j)
            stout(dout, out2_off + (long)wave * J2 + j, acc[2 + J1 + j] + us2f(ga[b2o + j]), f32);
    }
}

static inline dim3 g1(int total) { return dim3((unsigned)((total + 255) / 256)); }

extern "C" void kernel_launch(void* const* d_in, const int* in_sizes, int n_in,
                              void* d_out, int out_size, void* d_ws, size_t ws_size,
                              hipStream_t stream)
{
    int woff[53];
    int acc = OFF_WTS;
    int mx = 0;
    for (int i = 3; i < 53; ++i) { woff[i] = acc; acc += in_sizes[i]; if (in_sizes[i] > mx) mx = in_sizes[i]; }

    detect_kern<<<1, 64, 0, stream>>>(d_in[0]);
    convert_kern<<<g1(12441600), 256, 0, stream>>>(d_in[0], OFF_IMGS, 12441600);
    convert_kern<<<g1(3538944), 256, 0, stream>>>(d_in[1], OFF_C24, 3538944);
    convert_kern<<<g1(3538944), 256, 0, stream>>>(d_in[2], OFF_C48, 3538944);
    CvtTab tab;
    for (int i = 3; i < 53; ++i) tab.e[i - 3] = CvtEnt{ d_in[i], woff[i], in_sizes[i] };
    convert_many_kern<<<dim3((unsigned)((mx + 255) / 256), 50), 256, 0, stream>>>(tab);

    // ================= PNet =================
    pnet_c1p_kern<<<dim3(8, 23, 23), 256, 0, stream>>>(woff[3], woff[4], woff[5], OFF_A);
    pnet_c2_kern<<<dim3(8, 12, 12), 256, 0, stream>>>(OFF_A, woff[6], woff[7], woff[8], OFF_B);
    pnet_c3h_kern<<<dim3(8, 45, 12), 256, 0, stream>>>(OFF_B,
        woff[9], woff[10], woff[11], woff[12], woff[13], woff[14], woff[15], d_out);

    // ================= RNet =================
    conv_a_kern<3,3,3,24,24,22,22,28,32,4><<<dim3(2048, 4, 1), 256, 0, stream>>>(
        OFF_C24, woff[16], woff[17], woff[18], OFF_A);
    maxpool_kern<<<g1(6938624), 256, 0, stream>>>(OFF_A, OFF_B, 22, 22, 11, 11, 3, 2, 6938624);
    conv_a_kern<28,3,3,11,11,9,9,48,48,3><<<dim3(2048, 1, 1), 256, 0, stream>>>(
        OFF_B, woff[19], woff[20], woff[21], OFF_A);
    maxpool_kern<<<g1(1572864), 256, 0, stream>>>(OFF_A, OFF_B, 9, 9, 4, 4, 3, 2, 1572864);
    conv_a_kern<48,2,2,4,4,3,3,64,64,1><<<dim3(2048, 1, 1), 256, 0, stream>>>(
        OFF_B, woff[22], woff[23], woff[24], OFF_A);
    flatten_kern<<<g1(1179648), 256, 0, stream>>>(OFF_A, OFF_B, 64, 3, 3, 1179648);
    dense_tile_kern<<<dim3(64, 4), 256, 0, stream>>>(OFF_B, woff[25], woff[26], woff[27], OFF_A,
        576, 128);
    heads_wave_kern<128,4,0><<<dim3(512), 256, 0, stream>>>(OFF_A,
        woff[28], woff[29], woff[30], woff[31], 0, 0,
        d_out, 6057392L, 6049200L, 0L, 2048);

    // ================= ONet =================
    conv_a_kern<3,3,3,48,48,46,46,32,32,4><<<dim3(512, 17, 1), 256, 0, stream>>>(
        OFF_C48, woff[32], woff[33], woff[34], OFF_A);
    maxpool_kern<<<g1(8667136), 256, 0, stream>>>(OFF_A, OFF_B, 46, 46, 23, 23, 3, 2, 8667136);
    conv_a_kern<32,3,3,23,23,21,21,64,32,4><<<dim3(512, 4, 2), 256, 0, stream>>>(
        OFF_B, woff[35], woff[36], woff[37], OFF_A);
    maxpool_kern<<<g1(3276800), 256, 0, stream>>>(OFF_A, OFF_B, 21, 21, 10, 10, 3, 2, 3276800);
    conv_a_kern<64,3,3,10,10,8,8,64,16,2><<<dim3(512, 1, 4), 256, 0, stream>>>(
        OFF_B, woff[38], woff[39], woff[40], OFF_A);
    maxpool_kern<<<g1(524288), 256, 0, stream>>>(OFF_A, OFF_B, 8, 8, 4, 4, 2, 2, 524288);
    conv_a_kern<64,2,2,4,4,3,3,128,64,1><<<dim3(512, 1, 2), 256, 0, stream>>>(
        OFF_B, woff[41], woff[42], woff[43], OFF_A);
    flatten_kern<<<g1(589824), 256, 0, stream>>>(OFF_A, OFF_B, 128, 3, 3, 589824);
    dense_tile_kern<<<dim3(16, 8), 256, 0, stream>>>(OFF_B, woff[44], woff[45], woff[46], OFF_A,
        1152, 256);
    heads_wave_kern<256,4,10><<<dim3(128), 256, 0, stream>>>(OFF_A,
        woff[47], woff[48], woff[49], woff[50], woff[51], woff[52],
        d_out, 6068656L, 6061488L, 6063536L, 512);
}

// Round 8
// 1752.213 us; speedup vs baseline: 1.0724x; 1.0724x over previous
//
#include <hip/hip_runtime.h>
#include <hip/hip_bf16.h>

typedef __hip_bfloat16 bf16;
typedef unsigned short u16;
typedef unsigned int u32;

__device__ __forceinline__ float b2f(bf16 v) { return __bfloat162float(v); }
__device__ __forceinline__ bf16  f2b(float v) { return __float2bfloat16(v); }
__device__ __forceinline__ float us2f(u16 u) { return __uint_as_float((u32)u << 16); }
__device__ __forceinline__ float ulo(u32 u)  { return __uint_as_float(u << 16); }
__device__ __forceinline__ float uhi(u32 u)  { return __uint_as_float(u & 0xFFFF0000u); }

// ---------------------------------------------------------------------------
// Static device arena (BSS, ~143 MB): converted inputs + weights + scratch.
// ---------------------------------------------------------------------------
#define OFF_IMGS 0
#define OFF_C24  12441600
#define OFF_C48  15980544
#define OFF_WTS  19519488
#define OFF_A    20119488
#define OFF_B    54819488
#define ARENA_N  71319488L

__device__ bf16 g_arena[ARENA_N];
__device__ int  g_isf32;

// ---------------------------------------------------------------------------
// Dtype detection (bf16 N(0,1) never has exponent >= 0x8D; fp32 misread does).
// ---------------------------------------------------------------------------
__global__ void detect_kern(const void* imgs)
{
    if (threadIdx.x != 0) return;
    const u16* u = (const u16*)imgs;
    int f32 = 0;
    for (int i = 0; i < 256; ++i) {
        int e = (u[i] >> 7) & 0xFF;
        if (e >= 0x8D) f32 = 1;
    }
    g_isf32 = f32;
}

__global__ void convert_kern(const void* __restrict__ src, int dst_off, int n)
{
    int i = blockIdx.x * blockDim.x + threadIdx.x;
    if (i >= n) return;
    float v = g_isf32 ? ((const float*)src)[i] : b2f(((const bf16*)src)[i]);
    g_arena[(long)dst_off + i] = f2b(v);
}

struct CvtEnt { const void* src; int dst_off; int n; };
struct CvtTab { CvtEnt e[50]; };
__global__ void convert_many_kern(CvtTab tab)
{
    CvtEnt ent = tab.e[blockIdx.y];
    int i = blockIdx.x * blockDim.x + threadIdx.x;
    if (i >= ent.n) return;
    float v = g_isf32 ? ((const float*)ent.src)[i] : b2f(((const bf16*)ent.src)[i]);
    g_arena[(long)ent.dst_off + i] = f2b(v);
}

__device__ __forceinline__ void stout(void* base, long idx, float v, int f32)
{
    if (f32) ((float*)base)[idx] = v;
    else     ((bf16*)base)[idx] = f2b(v);
}

// ---------------------------------------------------------------------------
// Generic LDS-resident conv for crop nets (whole image fits in LDS).
// ---------------------------------------------------------------------------
template<int CIN,int KH,int KW,int H,int W,int OH,int OW,int CO,int OBLK,int R>
__launch_bounds__(256)
__global__ void conv_a_kern(int in_off, int w_off, int b_off, int a_off, int out_off)
{
    constexpr int KTOT = CIN * KH * KW;
    constexpr int INCNT = CIN * H * W;
    constexpr int OPT = OBLK / 8;
    constexpr int NPX = OH * OW;
    __shared__ __align__(16) u16 in_s[INCNT];
    __shared__ __align__(16) u16 w_s[KTOT * OBLK];

    int n = blockIdx.x, pxc = blockIdx.y, oc = blockIdx.z;
    const u16* ga = (const u16*)g_arena;

    const u32* src = (const u32*)(ga + in_off + (long)n * INCNT);
    u32* dst = (u32*)in_s;
    for (int i = threadIdx.x; i < INCNT / 2; i += 256) dst[i] = src[i];
    for (int i = threadIdx.x; i < KTOT * OBLK; i += 256) {
        int o_l = i % OBLK, k = i / OBLK;
        int o = oc * OBLK + o_l;
        w_s[i] = (o < CO) ? ga[w_off + (long)o * KTOT + k] : (u16)0;
    }
    __syncthreads();

    int lane = threadIdx.x & 31, og = threadIdx.x >> 5;
    int pixoff[R], pxg[R];
    bool vld[R];
    #pragma unroll
    for (int r = 0; r < R; ++r) {
        int px = pxc * (32 * R) + lane + r * 32;
        vld[r] = px < NPX;
        int p = vld[r] ? px : 0;
        pxg[r] = p;
        pixoff[r] = (p / OW) * W + (p % OW);
    }
    float acc[R][OPT];
    #pragma unroll
    for (int r = 0; r < R; ++r)
        #pragma unroll
        for (int j = 0; j < OPT; ++j) acc[r][j] = 0.f;

    const u32* wu = (const u32*)w_s;
    for (int c = 0; c < CIN; ++c) {
        #pragma unroll
        for (int ky = 0; ky < KH; ++ky) {
            #pragma unroll
            for (int kx = 0; kx < KW; ++kx) {
                int k = (c * KH + ky) * KW + kx;
                int ub = c * (H * W) + ky * W + kx;
                float a[R];
                #pragma unroll
                for (int r = 0; r < R; ++r) a[r] = us2f(in_s[ub + pixoff[r]]);
                int wb = (k * OBLK + og * OPT) >> 1;
                float wv[OPT];
                #pragma unroll
                for (int jj = 0; jj < OPT / 2; ++jj) {
                    u32 u = wu[wb + jj];
                    wv[2 * jj] = ulo(u); wv[2 * jj + 1] = uhi(u);
                }
                #pragma unroll
                for (int r = 0; r < R; ++r)
                    #pragma unroll
                    for (int j = 0; j < OPT; ++j)
                        acc[r][j] += a[r] * wv[j];
            }
        }
    }
    #pragma unroll
    for (int j = 0; j < OPT; ++j) {
        int o = oc * OBLK + og * OPT + j;
        if (o < CO) {
            float b = us2f(ga[b_off + o]);
            float al = us2f(ga[a_off + o]);
            #pragma unroll
            for (int r = 0; r < R; ++r) if (vld[r]) {
                float v = acc[r][j] + b;
                v = v > 0.f ? v : v * al;
                g_arena[(long)out_off + ((long)n * CO + o) * NPX + pxg[r]] = f2b(v);
            }
        }
    }
}

// ---------------------------------------------------------------------------
// PNet conv1 (3->10) + PReLU + maxpool 2x2 s2.
// ---------------------------------------------------------------------------
__launch_bounds__(256)
__global__ void pnet_c1p_kern(int w_off, int b_off, int a_off, int out_off)
{
    __shared__ u16 patch[3 * 34 * 34];
    __shared__ __align__(16) u16 w_s[27 * 16];
    int n = blockIdx.x, pty = blockIdx.y, ptx = blockIdx.z;
    int cy0 = pty * 32, cx0 = ptx * 32;
    const u16* ga = (const u16*)g_arena;

    for (int i = threadIdx.x; i < 3468; i += 256) {
        int c = i / 1156, rem = i % 1156, py = rem / 34, pxx = rem % 34;
        int iy = cy0 + py, ix = cx0 + pxx;
        u16 v = 0;
        if (iy < 720 && ix < 720)
            v = ga[OFF_IMGS + ((long)(n * 3 + c) * 720 + iy) * 720 + ix];
        patch[i] = v;
    }
    for (int i = threadIdx.x; i < 27 * 16; i += 256) {
        int o = i % 16, k = i / 16;
        w_s[i] = (o < 10) ? ga[w_off + o * 27 + k] : (u16)0;
    }
    __syncthreads();

    int px = threadIdx.x % 16, py = threadIdx.x / 16;
    float acc[2][2][10];
    #pragma unroll
    for (int a = 0; a < 2; ++a)
        #pragma unroll
        for (int b = 0; b < 2; ++b)
            #pragma unroll
            for (int o = 0; o < 10; ++o) acc[a][b][o] = 0.f;

    const uint4* wq = (const uint4*)w_s;
    for (int c = 0; c < 3; ++c) {
        #pragma unroll
        for (int ky = 0; ky < 3; ++ky) {
            #pragma unroll
            for (int kx = 0; kx < 3; ++kx) {
                int k = (c * 3 + ky) * 3 + kx;
                float a[2][2];
                #pragma unroll
                for (int dy = 0; dy < 2; ++dy)
                    #pragma unroll
                    for (int dx = 0; dx < 2; ++dx)
                        a[dy][dx] = us2f(patch[c * 1156 + (2 * py + dy + ky) * 34 + (2 * px + dx + kx)]);
                uint4 q0 = wq[k * 2], q1 = wq[k * 2 + 1];
                float wv[10];
                wv[0] = ulo(q0.x); wv[1] = uhi(q0.x); wv[2] = ulo(q0.y); wv[3] = uhi(q0.y);
                wv[4] = ulo(q0.z); wv[5] = uhi(q0.z); wv[6] = ulo(q0.w); wv[7] = uhi(q0.w);
                wv[8] = ulo(q1.x); wv[9] = uhi(q1.x);
                #pragma unroll
                for (int o = 0; o < 10; ++o)
                    #pragma unroll
                    for (int dy = 0; dy < 2; ++dy)
                        #pragma unroll
                        for (int dx = 0; dx < 2; ++dx)
                            acc[dy][dx][o] += a[dy][dx] * wv[o];
            }
        }
    }
    int pgy = pty * 16 + py, pgx = ptx * 16 + px;
    if (pgy < 359 && pgx < 359) {
        #pragma unroll
        for (int o = 0; o < 10; ++o) {
            float b = us2f(ga[b_off + o]);
            float al = us2f(ga[a_off + o]);
            float m = -1e30f;
            #pragma unroll
            for (int dy = 0; dy < 2; ++dy)
                #pragma unroll
                for (int dx = 0; dx < 2; ++dx) {
                    float v = acc[dy][dx][o] + b;
                    v = v > 0.f ? v : v * al;
                    m = fmaxf(m, v);
                }
            g_arena[(long)out_off + ((long)(n * 10 + o) * 359 + pgy) * 359 + pgx] = f2b(m);
        }
    }
}

// ---------------------------------------------------------------------------
// PNet conv2 (10->16).
// ---------------------------------------------------------------------------
__launch_bounds__(256)
__global__ void pnet_c2_kern(int in_off, int w_off, int b_off, int a_off, int out_off)
{
    __shared__ u16 patch[10 * 34 * 34];
    __shared__ __align__(16) u16 w_s[90 * 16];
    int n = blockIdx.x, ty = blockIdx.y, tx = blockIdx.z;
    int y0 = ty * 32, x0 = tx * 32;
    const u16* ga = (const u16*)g_arena;

    for (int i = threadIdx.x; i < 11560; i += 256) {
        int c = i / 1156, rem = i % 1156, py = rem / 34, pxx = rem % 34;
        int iy = y0 + py, ix = x0 + pxx;
        u16 v = 0;
        if (iy < 359 && ix < 359)
            v = ga[in_off + ((long)(n * 10 + c) * 359 + iy) * 359 + ix];
        patch[i] = v;
    }
    for (int i = threadIdx.x; i < 1440; i += 256) {
        int o = i % 16, k = i / 16;
        w_s[i] = ga[w_off + o * 90 + k];
    }
    __syncthreads();

    int x = threadIdx.x % 32, yg = threadIdx.x / 32;
    float acc[4][16];
    #pragma unroll
    for (int r = 0; r < 4; ++r)
        #pragma unroll
        for (int o = 0; o < 16; ++o) acc[r][o] = 0.f;

    const uint4* wq = (const uint4*)w_s;
    for (int c = 0; c < 10; ++c) {
        #pragma unroll
        for (int ky = 0; ky < 3; ++ky) {
            #pragma unroll
            for (int kx = 0; kx < 3; ++kx) {
                int k = (c * 3 + ky) * 3 + kx;
                float a[4];
                #pragma unroll
                for (int r = 0; r < 4; ++r)
                    a[r] = us2f(patch[c * 1156 + (yg + 8 * r + ky) * 34 + (x + kx)]);
                uint4 q0 = wq[k * 2], q1 = wq[k * 2 + 1];
                float wv[16];
                wv[0]=ulo(q0.x); wv[1]=uhi(q0.x); wv[2]=ulo(q0.y); wv[3]=uhi(q0.y);
                wv[4]=ulo(q0.z); wv[5]=uhi(q0.z); wv[6]=ulo(q0.w); wv[7]=uhi(q0.w);
                wv[8]=ulo(q1.x); wv[9]=uhi(q1.x); wv[10]=ulo(q1.y); wv[11]=uhi(q1.y);
                wv[12]=ulo(q1.z); wv[13]=uhi(q1.z); wv[14]=ulo(q1.w); wv[15]=uhi(q1.w);
                #pragma unroll
                for (int r = 0; r < 4; ++r)
                    #pragma unroll
                    for (int o = 0; o < 16; ++o)
                        acc[r][o] += a[r] * wv[o];
            }
        }
    }
    #pragma unroll
    for (int o = 0; o < 16; ++o) {
        float b = us2f(ga[b_off + o]);
        float al = us2f(ga[a_off + o]);
        #pragma unroll
        for (int r = 0; r < 4; ++r) {
            int gy = y0 + yg + 8 * r, gx = x0 + x;
            if (gy < 357 && gx < 357) {
                float v = acc[r][o] + b;
                v = v > 0.f ? v : v * al;
                g_arena[(long)out_off + ((long)(n * 16 + o) * 357 + gy) * 357 + gx] = f2b(v);
            }
        }
    }
}

// ---------------------------------------------------------------------------
// PNet conv3 (16->32) + PReLU + 1x1 heads + softmax, fused.
// (round-6 version: fp32 c3s[p*33+o] — the bf16-transposed variant regressed)
// ---------------------------------------------------------------------------
__launch_bounds__(256)
__global__ void pnet_c3h_kern(int in_off, int w3o, int b3o, int a3o,
                              int w41o, int b41o, int w42o, int b42o, void* dout)
{
    __shared__ u16 patch[16 * 10 * 34];
    __shared__ __align__(16) u16 w3s[144 * 32];
    __shared__ float c3s[256 * 33];
    __shared__ float b3f[32], a3f[32], w41f[64], w42f[128], b41f[2], b42f[4];

    int n = blockIdx.x, by = blockIdx.y, tx = blockIdx.z;
    int gy0 = by * 8, gx0 = tx * 32;
    const u16* ga = (const u16*)g_arena;

    for (int i = threadIdx.x; i < 5440; i += 256) {
        int c = i / 340, rem = i % 340, py = rem / 34, pxx = rem % 34;
        int iy = gy0 + py, ix = gx0 + pxx;
        u16 v = 0;
        if (iy < 357 && ix < 357)
            v = ga[in_off + ((long)(n * 16 + c) * 357 + iy) * 357 + ix];
        patch[i] = v;
    }
    for (int i = threadIdx.x; i < 4608; i += 256) {
        int o = i % 32, k = i / 32;
        w3s[i] = ga[w3o + o * 144 + k];
    }
    for (int i = threadIdx.x; i < 32; i += 256) { b3f[i] = us2f(ga[b3o + i]); a3f[i] = us2f(ga[a3o + i]); }
    for (int i = threadIdx.x; i < 64; i += 256) w41f[i] = us2f(ga[w41o + i]);
    for (int i = threadIdx.x; i < 128; i += 256) w42f[i] = us2f(ga[w42o + i]);
    if (threadIdx.x < 2) b41f[threadIdx.x] = us2f(ga[b41o + threadIdx.x]);
    if (threadIdx.x < 4) b42f[threadIdx.x] = us2f(ga[b42o + threadIdx.x]);
    __syncthreads();

    int lane = threadIdx.x & 63, og = threadIdx.x >> 6;
    int pb[4];
    #pragma unroll
    for (int r = 0; r < 4; ++r) {
        int p = lane + 64 * r;
        pb[r] = (p >> 5) * 34 + (p & 31);
    }
    float acc[4][8];
    #pragma unroll
    for (int r = 0; r < 4; ++r)
        #pragma unroll
        for (int j = 0; j < 8; ++j) acc[r][j] = 0.f;

    const uint4* wq = (const uint4*)w3s;
    for (int c = 0; c < 16; ++c) {
        #pragma unroll
        for (int ky = 0; ky < 3; ++ky) {
            #pragma unroll
            for (int kx = 0; kx < 3; ++kx) {
                int k = (c * 3 + ky) * 3 + kx;
                int ub = c * 340 + ky * 34 + kx;
                float a[4];
                #pragma unroll
                for (int r = 0; r < 4; ++r) a[r] = us2f(patch[ub + pb[r]]);
                uint4 q = wq[k * 4 + og];
                float wv[8];
                wv[0]=ulo(q.x); wv[1]=uhi(q.x); wv[2]=ulo(q.y); wv[3]=uhi(q.y);
                wv[4]=ulo(q.z); wv[5]=uhi(q.z); wv[6]=ulo(q.w); wv[7]=uhi(q.w);
                #pragma unroll
                for (int r = 0; r < 4; ++r)
                    #pragma unroll
                    for (int j = 0; j < 8; ++j)
                        acc[r][j] += a[r] * wv[j];
            }
        }
    }
    #pragma unroll
    for (int j = 0; j < 8; ++j) {
        int o = og * 8 + j;
        float b = b3f[o], al = a3f[o];
        #pragma unroll
        for (int r = 0; r < 4; ++r) {
            int p = lane + 64 * r;
            float v = acc[r][j] + b;
            v = v > 0.f ? v : v * al;
            c3s[p * 33 + o] = v;
        }
    }
    __syncthreads();

    int p = threadIdx.x;
    int gy = gy0 + (p >> 5), gx = gx0 + (p & 31);
    if (gy < 355 && gx < 355) {
        int f32 = g_isf32;
        float l0 = b41f[0], l1 = b41f[1];
        float r0 = b42f[0], r1 = b42f[1], r2 = b42f[2], r3 = b42f[3];
        #pragma unroll
        for (int o = 0; o < 32; ++o) {
            float v = c3s[p * 33 + o];
            l0 += v * w41f[o];
            l1 += v * w41f[32 + o];
            r0 += v * w42f[o];
            r1 += v * w42f[32 + o];
            r2 += v * w42f[64 + o];
            r3 += v * w42f[96 + o];
        }
        float mx = fmaxf(l0, l1);
        float e0 = __expf(l0 - mx), e1 = __expf(l1 - mx);
        float inv = 1.f / (e0 + e1);
        const long HW = 355L * 355L;
        long pix = (long)gy * 355 + gx;
        stout(dout, 4032800 + ((long)n * 2 + 0) * HW + pix, e0 * inv, f32);
        stout(dout, 4032800 + ((long)n * 2 + 1) * HW + pix, e1 * inv, f32);
        stout(dout, ((long)n * 4 + 0) * HW + pix, r0, f32);
        stout(dout, ((long)n * 4 + 1) * HW + pix, r1, f32);
        stout(dout, ((long)n * 4 + 2) * HW + pix, r2, f32);
        stout(dout, ((long)n * 4 + 3) * HW + pix, r3, f32);
    }
}

// ---------------------------------------------------------------------------
// MaxPool2d, ceil_mode (OOB taps skipped).
// ---------------------------------------------------------------------------
__global__ void maxpool_kern(int in_off, int out_off,
                             int H, int W, int OH, int OW, int k, int s, int total)
{
    int tid = blockIdx.x * blockDim.x + threadIdx.x;
    if (tid >= total) return;
    int x = tid % OW;
    int t = tid / OW;
    int y = t % OH;
    int nc = t / OH;
    const bf16* ip = g_arena + in_off + (long)nc * H * W;
    int sy = y * s, sx = x * s;
    float m = -1e30f;
    for (int ky = 0; ky < k; ++ky) {
        int iy = sy + ky;
        if (iy >= H) break;
        for (int kx = 0; kx < k; ++kx) {
            int ix = sx + kx;
            if (ix >= W) break;
            m = fmaxf(m, b2f(ip[iy * W + ix]));
        }
    }
    g_arena[(long)out_off + tid] = f2b(m);
}

// ---------------------------------------------------------------------------
// Flatten: torch permute(0,3,2,1).view -> out[n][w*H*C + h*C + c]
// ---------------------------------------------------------------------------
__global__ void flatten_kern(int in_off, int out_off, int C, int H, int W, int total)
{
    int tid = blockIdx.x * blockDim.x + threadIdx.x;
    if (tid >= total) return;
    int CHW = C * H * W;
    int n = tid / CHW;
    int k = tid % CHW;
    int w = k / (H * C);
    int r = k % (H * C);
    int h = r / C;
    int c = r % C;
    g_arena[(long)out_off + tid] = g_arena[in_off + (((long)n * C + c) * H + h) * W + w];
}

// ---------------------------------------------------------------------------
// Dense + bias + PReLU as tiled LDS GEMM (32x32 tile, 2x2 micro-tile).
// ---------------------------------------------------------------------------
__launch_bounds__(256)
__global__ void dense_tile_kern(int in_off, int w_off, int b_off, int a_off, int out_off,
                                int K, int J)
{
    __shared__ u16 in_s[32 * 66];
    __shared__ u16 w_s[32 * 66];
    int n0 = blockIdx.x * 32, j0 = blockIdx.y * 32;
    const u16* ga = (const u16*)g_arena;
    const u16* fin = ga + in_off;
    const u16* wts = ga + w_off;
    int sy = threadIdx.x >> 4, sx = threadIdx.x & 15;

    float acc00 = 0.f, acc01 = 0.f, acc10 = 0.f, acc11 = 0.f;

    for (int kc = 0; kc < K; kc += 64) {
        #pragma unroll
        for (int it = 0; it < 4; ++it) {
            int i = threadIdx.x + it * 256;
            int row = i >> 5, c2 = i & 31;
            u32 v = *(const u32*)(fin + (long)(n0 + row) * K + kc + c2 * 2);
            *(u32*)&in_s[row * 66 + c2 * 2] = v;
            u32 wv = *(const u32*)(wts + (long)(j0 + row) * K + kc + c2 * 2);
            *(u32*)&w_s[row * 66 + c2 * 2] = wv;
        }
        __syncthreads();
        #pragma unroll
        for (int kk = 0; kk < 64; ++kk) {
            float a0 = us2f(in_s[(2 * sy) * 66 + kk]);
            float a1 = us2f(in_s[(2 * sy + 1) * 66 + kk]);
            float b0 = us2f(w_s[(2 * sx) * 66 + kk]);
            float b1 = us2f(w_s[(2 * sx + 1) * 66 + kk]);
            acc00 += a0 * b0; acc01 += a0 * b1;
            acc10 += a1 * b0; acc11 += a1 * b1;
        }
        __syncthreads();
    }

    float accs[2][2] = {{acc00, acc01}, {acc10, acc11}};
    #pragma unroll
    for (int jj = 0; jj < 2; ++jj) {
        int j = j0 + 2 * sx + jj;
        float b = us2f(ga[b_off + j]);
        float al = us2f(ga[a_off + j]);
        #pragma unroll
        for (int ss = 0; ss < 2; ++ss) {
            int n = n0 + 2 * sy + ss;
            float v = accs[ss][jj] + b;
            v = v > 0.f ? v : v * al;
            g_arena[(long)out_off + (long)n * J + j] = f2b(v);
        }
    }
}

// ---------------------------------------------------------------------------
// Heads, wave-per-sample: 64 lanes partition K; butterfly shuffle reduction.
// ---------------------------------------------------------------------------
template<int K, int J1, int J2>
__launch_bounds__(256)
__global__ void heads_wave_kern(int fc_off, int wSo, int bSo, int w1o, int b1o,
                                int w2o, int b2o, void* dout,
                                long outS_off, long out1_off, long out2_off, int N)
{
    constexpr int KPL = K / 64;
    constexpr int NACC = 2 + J1 + J2;
    int wave = (blockIdx.x * blockDim.x + threadIdx.x) >> 6;
    int lane = threadIdx.x & 63;
    if (wave >= N) return;
    const u16* ga = (const u16*)g_arena;
    const u16* f  = ga + fc_off + (long)wave * K;
    const u16* wS = ga + wSo;
    const u16* w1 = ga + w1o;
    const u16* w2 = ga + w2o;

    float acc[NACC];
    #pragma unroll
    for (int j = 0; j < NACC; ++j) acc[j] = 0.f;

    #pragma unroll
    for (int kk = 0; kk < KPL; ++kk) {
        int k = lane + kk * 64;
        float fv = us2f(f[k]);
        acc[0] += fv * us2f(wS[k]);
        acc[1] += fv * us2f(wS[K + k]);
        #pragma unroll
        for (int j = 0; j < J1; ++j)
            acc[2 + j] += fv * us2f(w1[j * K + k]);
        #pragma unroll
        for (int j = 0; j < J2; ++j)
            acc[2 + J1 + j] += fv * us2f(w2[j * K + k]);
    }
    #pragma unroll
    for (int j = 0; j < NACC; ++j)
        #pragma unroll
        for (int off = 32; off > 0; off >>= 1)
            acc[j] += __shfl_xor(acc[j], off, 64);

    if (lane == 0) {
        int f32 = g_isf32;
        float l0 = acc[0] + us2f(ga[bSo + 0]);
        float l1 = acc[1] + us2f(ga[bSo + 1]);
        float m = fmaxf(l0, l1);
        float e0 = __expf(l0 - m), e1 = __expf(l1 - m);
        float inv = 1.f / (e0 + e1);
        stout(dout, outS_off + (long)wave * 2 + 0, e0 * inv, f32);
        stout(dout, outS_off + (long)wave * 2 + 1, e1 * inv, f32);
        #pragma unroll
        for (int j = 0; j < J1; ++j)
            stout(dout, out1_off + (long)wave * J1 + j, acc[2 + j] + us2f(ga[b1o + j]), f32);
        #pragma unroll
        for (int j = 0; j < J2; ++j)
            stout(dout, out2_off + (long)wave * J2 + j, acc[2 + J1 + j] + us2f(ga[b2o + j]), f32);
    }
}

static inline dim3 g1(int total) { return dim3((unsigned)((total + 255) / 256)); }

extern "C" void kernel_launch(void* const* d_in, const int* in_sizes, int n_in,
                              void* d_out, int out_size, void* d_ws, size_t ws_size,
                              hipStream_t stream)
{
    int woff[53];
    int acc = OFF_WTS;
    int mx = 0;
    for (int i = 3; i < 53; ++i) { woff[i] = acc; acc += in_sizes[i]; if (in_sizes[i] > mx) mx = in_sizes[i]; }

    detect_kern<<<1, 64, 0, stream>>>(d_in[0]);
    convert_kern<<<g1(12441600), 256, 0, stream>>>(d_in[0], OFF_IMGS, 12441600);
    convert_kern<<<g1(3538944), 256, 0, stream>>>(d_in[1], OFF_C24, 3538944);
    convert_kern<<<g1(3538944), 256, 0, stream>>>(d_in[2], OFF_C48, 3538944);
    CvtTab tab;
    for (int i = 3; i < 53; ++i) tab.e[i - 3] = CvtEnt{ d_in[i], woff[i], in_sizes[i] };
    convert_many_kern<<<dim3((unsigned)((mx + 255) / 256), 50), 256, 0, stream>>>(tab);

    // ================= PNet =================
    pnet_c1p_kern<<<dim3(8, 23, 23), 256, 0, stream>>>(woff[3], woff[4], woff[5], OFF_A);
    pnet_c2_kern<<<dim3(8, 12, 12), 256, 0, stream>>>(OFF_A, woff[6], woff[7], woff[8], OFF_B);
    pnet_c3h_kern<<<dim3(8, 45, 12), 256, 0, stream>>>(OFF_B,
        woff[9], woff[10], woff[11], woff[12], woff[13], woff[14], woff[15], d_out);

    // ================= RNet =================
    conv_a_kern<3,3,3,24,24,22,22,28,32,4><<<dim3(2048, 4, 1), 256, 0, stream>>>(
        OFF_C24, woff[16], woff[17], woff[18], OFF_A);
    maxpool_kern<<<g1(6938624), 256, 0, stream>>>(OFF_A, OFF_B, 22, 22, 11, 11, 3, 2, 6938624);
    conv_a_kern<28,3,3,11,11,9,9,48,48,3><<<dim3(2048, 1, 1), 256, 0, stream>>>(
        OFF_B, woff[19], woff[20], woff[21], OFF_A);
    maxpool_kern<<<g1(1572864), 256, 0, stream>>>(OFF_A, OFF_B, 9, 9, 4, 4, 3, 2, 1572864);
    conv_a_kern<48,2,2,4,4,3,3,64,64,1><<<dim3(2048, 1, 1), 256, 0, stream>>>(
        OFF_B, woff[22], woff[23], woff[24], OFF_A);
    flatten_kern<<<g1(1179648), 256, 0, stream>>>(OFF_A, OFF_B, 64, 3, 3, 1179648);
    dense_tile_kern<<<dim3(64, 4), 256, 0, stream>>>(OFF_B, woff[25], woff[26], woff[27], OFF_A,
        576, 128);
    heads_wave_kern<128,4,0><<<dim3(512), 256, 0, stream>>>(OFF_A,
        woff[28], woff[29], woff[30], woff[31], 0, 0,
        d_out, 6057392L, 6049200L, 0L, 2048);

    // ================= ONet =================
    conv_a_kern<3,3,3,48,48,46,46,32,32,4><<<dim3(512, 17, 1), 256, 0, stream>>>(
        OFF_C48, woff[32], woff[33], woff[34], OFF_A);
    maxpool_kern<<<g1(8667136), 256, 0, stream>>>(OFF_A, OFF_B, 46, 46, 23, 23, 3, 2, 8667136);
    conv_a_kern<32,3,3,23,23,21,21,64,32,4><<<dim3(512, 4, 2), 256, 0, stream>>>(
        OFF_B, woff[35], woff[36], woff[37], OFF_A);
    maxpool_kern<<<g1(3276800), 256, 0, stream>>>(OFF_A, OFF_B, 21, 21, 10, 10, 3, 2, 3276800);
    conv_a_kern<64,3,3,10,10,8,8,64,16,2><<<dim3(512, 1, 4), 256, 0, stream>>>(
        OFF_B, woff[38], woff[39], woff[40], OFF_A);
    maxpool_kern<<<g1(524288), 256, 0, stream>>>(OFF_A, OFF_B, 8, 8, 4, 4, 2, 2, 524288);
    conv_a_kern<64,2,2,4,4,3,3,128,64,1><<<dim3(512, 1, 2), 256, 0, stream>>>(
        OFF_B, woff[41], woff[42], woff[43], OFF_A);
    flatten_kern<<<g1(589824), 256, 0, stream>>>(OFF_A, OFF_B, 128, 3, 3, 589824);
    dense_tile_kern<<<dim3(16, 8), 256, 0, stream>>>(OFF_B, woff[44], woff[45], woff[46], OFF_A,
        1152, 256);
    heads_wave_kern<256,4,10><<<dim3(128), 256, 0, stream>>>(OFF_A,
        woff[47], woff[48], woff[49], woff[50], woff[51], woff[52],
        d_out, 6068656L, 6061488L, 6063536L, 512);
}

// Round 9
// 1642.837 us; speedup vs baseline: 1.1439x; 1.0666x over previous
//
#include <hip/hip_runtime.h>
#include <hip/hip_bf16.h>

typedef __hip_bfloat16 bf16;
typedef unsigned short u16;
typedef unsigned int u32;

typedef float f32x16 __attribute__((ext_vector_type(16)));
typedef short s16x8 __attribute__((ext_vector_type(8)));

__device__ __forceinline__ float b2f(bf16 v) { return __bfloat162float(v); }
__device__ __forceinline__ bf16  f2b(float v) { return __float2bfloat16(v); }
__device__ __forceinline__ float us2f(u16 u) { return __uint_as_float((u32)u << 16); }
__device__ __forceinline__ float ulo(u32 u)  { return __uint_as_float(u << 16); }
__device__ __forceinline__ float uhi(u32 u)  { return __uint_as_float(u & 0xFFFF0000u); }

// ---------------------------------------------------------------------------
// Static device arena (BSS, ~143 MB): converted inputs + weights + scratch.
// ---------------------------------------------------------------------------
#define OFF_IMGS 0
#define OFF_C24  12441600
#define OFF_C48  15980544
#define OFF_WTS  19519488
#define OFF_A    20119488
#define OFF_B    54819488
#define ARENA_N  71319488L

__device__ bf16 g_arena[ARENA_N];
__device__ int  g_isf32;

// ---------------------------------------------------------------------------
// Dtype detection (bf16 N(0,1) never has exponent >= 0x8D; fp32 misread does).
// ---------------------------------------------------------------------------
__global__ void detect_kern(const void* imgs)
{
    if (threadIdx.x != 0) return;
    const u16* u = (const u16*)imgs;
    int f32 = 0;
    for (int i = 0; i < 256; ++i) {
        int e = (u[i] >> 7) & 0xFF;
        if (e >= 0x8D) f32 = 1;
    }
    g_isf32 = f32;
}

__global__ void convert_kern(const void* __restrict__ src, int dst_off, int n)
{
    int i = blockIdx.x * blockDim.x + threadIdx.x;
    if (i >= n) return;
    float v = g_isf32 ? ((const float*)src)[i] : b2f(((const bf16*)src)[i]);
    g_arena[(long)dst_off + i] = f2b(v);
}

struct CvtEnt { const void* src; int dst_off; int n; };
struct CvtTab { CvtEnt e[50]; };
__global__ void convert_many_kern(CvtTab tab)
{
    CvtEnt ent = tab.e[blockIdx.y];
    int i = blockIdx.x * blockDim.x + threadIdx.x;
    if (i >= ent.n) return;
    float v = g_isf32 ? ((const float*)ent.src)[i] : b2f(((const bf16*)ent.src)[i]);
    g_arena[(long)ent.dst_off + i] = f2b(v);
}

__device__ __forceinline__ void stout(void* base, long idx, float v, int f32)
{
    if (f32) ((float*)base)[idx] = v;
    else     ((bf16*)base)[idx] = f2b(v);
}

// ---------------------------------------------------------------------------
// Generic LDS-resident conv for crop nets (whole image fits in LDS).
// ---------------------------------------------------------------------------
template<int CIN,int KH,int KW,int H,int W,int OH,int OW,int CO,int OBLK,int R>
__launch_bounds__(256)
__global__ void conv_a_kern(int in_off, int w_off, int b_off, int a_off, int out_off)
{
    constexpr int KTOT = CIN * KH * KW;
    constexpr int INCNT = CIN * H * W;
    constexpr int OPT = OBLK / 8;
    constexpr int NPX = OH * OW;
    __shared__ __align__(16) u16 in_s[INCNT];
    __shared__ __align__(16) u16 w_s[KTOT * OBLK];

    int n = blockIdx.x, pxc = blockIdx.y, oc = blockIdx.z;
    const u16* ga = (const u16*)g_arena;

    const u32* src = (const u32*)(ga + in_off + (long)n * INCNT);
    u32* dst = (u32*)in_s;
    for (int i = threadIdx.x; i < INCNT / 2; i += 256) dst[i] = src[i];
    for (int i = threadIdx.x; i < KTOT * OBLK; i += 256) {
        int o_l = i % OBLK, k = i / OBLK;
        int o = oc * OBLK + o_l;
        w_s[i] = (o < CO) ? ga[w_off + (long)o * KTOT + k] : (u16)0;
    }
    __syncthreads();

    int lane = threadIdx.x & 31, og = threadIdx.x >> 5;
    int pixoff[R], pxg[R];
    bool vld[R];
    #pragma unroll
    for (int r = 0; r < R; ++r) {
        int px = pxc * (32 * R) + lane + r * 32;
        vld[r] = px < NPX;
        int p = vld[r] ? px : 0;
        pxg[r] = p;
        pixoff[r] = (p / OW) * W + (p % OW);
    }
    float acc[R][OPT];
    #pragma unroll
    for (int r = 0; r < R; ++r)
        #pragma unroll
        for (int j = 0; j < OPT; ++j) acc[r][j] = 0.f;

    const u32* wu = (const u32*)w_s;
    for (int c = 0; c < CIN; ++c) {
        #pragma unroll
        for (int ky = 0; ky < KH; ++ky) {
            #pragma unroll
            for (int kx = 0; kx < KW; ++kx) {
                int k = (c * KH + ky) * KW + kx;
                int ub = c * (H * W) + ky * W + kx;
                float a[R];
                #pragma unroll
                for (int r = 0; r < R; ++r) a[r] = us2f(in_s[ub + pixoff[r]]);
                int wb = (k * OBLK + og * OPT) >> 1;
                float wv[OPT];
                #pragma unroll
                for (int jj = 0; jj < OPT / 2; ++jj) {
                    u32 u = wu[wb + jj];
                    wv[2 * jj] = ulo(u); wv[2 * jj + 1] = uhi(u);
                }
                #pragma unroll
                for (int r = 0; r < R; ++r)
                    #pragma unroll
                    for (int j = 0; j < OPT; ++j)
                        acc[r][j] += a[r] * wv[j];
            }
        }
    }
    #pragma unroll
    for (int j = 0; j < OPT; ++j) {
        int o = oc * OBLK + og * OPT + j;
        if (o < CO) {
            float b = us2f(ga[b_off + o]);
            float al = us2f(ga[a_off + o]);
            #pragma unroll
            for (int r = 0; r < R; ++r) if (vld[r]) {
                float v = acc[r][j] + b;
                v = v > 0.f ? v : v * al;
                g_arena[(long)out_off + ((long)n * CO + o) * NPX + pxg[r]] = f2b(v);
            }
        }
    }
}

// ---------------------------------------------------------------------------
// PNet conv1 (3->10) + PReLU + maxpool 2x2 s2.
// ---------------------------------------------------------------------------
__launch_bounds__(256)
__global__ void pnet_c1p_kern(int w_off, int b_off, int a_off, int out_off)
{
    __shared__ u16 patch[3 * 34 * 34];
    __shared__ __align__(16) u16 w_s[27 * 16];
    int n = blockIdx.x, pty = blockIdx.y, ptx = blockIdx.z;
    int cy0 = pty * 32, cx0 = ptx * 32;
    const u16* ga = (const u16*)g_arena;

    for (int i = threadIdx.x; i < 3468; i += 256) {
        int c = i / 1156, rem = i % 1156, py = rem / 34, pxx = rem % 34;
        int iy = cy0 + py, ix = cx0 + pxx;
        u16 v = 0;
        if (iy < 720 && ix < 720)
            v = ga[OFF_IMGS + ((long)(n * 3 + c) * 720 + iy) * 720 + ix];
        patch[i] = v;
    }
    for (int i = threadIdx.x; i < 27 * 16; i += 256) {
        int o = i % 16, k = i / 16;
        w_s[i] = (o < 10) ? ga[w_off + o * 27 + k] : (u16)0;
    }
    __syncthreads();

    int px = threadIdx.x % 16, py = threadIdx.x / 16;
    float acc[2][2][10];
    #pragma unroll
    for (int a = 0; a < 2; ++a)
        #pragma unroll
        for (int b = 0; b < 2; ++b)
            #pragma unroll
            for (int o = 0; o < 10; ++o) acc[a][b][o] = 0.f;

    const uint4* wq = (const uint4*)w_s;
    for (int c = 0; c < 3; ++c) {
        #pragma unroll
        for (int ky = 0; ky < 3; ++ky) {
            #pragma unroll
            for (int kx = 0; kx < 3; ++kx) {
                int k = (c * 3 + ky) * 3 + kx;
                float a[2][2];
                #pragma unroll
                for (int dy = 0; dy < 2; ++dy)
                    #pragma unroll
                    for (int dx = 0; dx < 2; ++dx)
                        a[dy][dx] = us2f(patch[c * 1156 + (2 * py + dy + ky) * 34 + (2 * px + dx + kx)]);
                uint4 q0 = wq[k * 2], q1 = wq[k * 2 + 1];
                float wv[10];
                wv[0] = ulo(q0.x); wv[1] = uhi(q0.x); wv[2] = ulo(q0.y); wv[3] = uhi(q0.y);
                wv[4] = ulo(q0.z); wv[5] = uhi(q0.z); wv[6] = ulo(q0.w); wv[7] = uhi(q0.w);
                wv[8] = ulo(q1.x); wv[9] = uhi(q1.x);
                #pragma unroll
                for (int o = 0; o < 10; ++o)
                    #pragma unroll
                    for (int dy = 0; dy < 2; ++dy)
                        #pragma unroll
                        for (int dx = 0; dx < 2; ++dx)
                            acc[dy][dx][o] += a[dy][dx] * wv[o];
            }
        }
    }
    int pgy = pty * 16 + py, pgx = ptx * 16 + px;
    if (pgy < 359 && pgx < 359) {
        #pragma unroll
        for (int o = 0; o < 10; ++o) {
            float b = us2f(ga[b_off + o]);
            float al = us2f(ga[a_off + o]);
            float m = -1e30f;
            #pragma unroll
            for (int dy = 0; dy < 2; ++dy)
                #pragma unroll
                for (int dx = 0; dx < 2; ++dx) {
                    float v = acc[dy][dx][o] + b;
                    v = v > 0.f ? v : v * al;
                    m = fmaxf(m, v);
                }
            g_arena[(long)out_off + ((long)(n * 10 + o) * 359 + pgy) * 359 + pgx] = f2b(m);
        }
    }
}

// ---------------------------------------------------------------------------
// PNet conv2 (10->16).
// ---------------------------------------------------------------------------
__launch_bounds__(256)
__global__ void pnet_c2_kern(int in_off, int w_off, int b_off, int a_off, int out_off)
{
    __shared__ u16 patch[10 * 34 * 34];
    __shared__ __align__(16) u16 w_s[90 * 16];
    int n = blockIdx.x, ty = blockIdx.y, tx = blockIdx.z;
    int y0 = ty * 32, x0 = tx * 32;
    const u16* ga = (const u16*)g_arena;

    for (int i = threadIdx.x; i < 11560; i += 256) {
        int c = i / 1156, rem = i % 1156, py = rem / 34, pxx = rem % 34;
        int iy = y0 + py, ix = x0 + pxx;
        u16 v = 0;
        if (iy < 359 && ix < 359)
            v = ga[in_off + ((long)(n * 10 + c) * 359 + iy) * 359 + ix];
        patch[i] = v;
    }
    for (int i = threadIdx.x; i < 1440; i += 256) {
        int o = i % 16, k = i / 16;
        w_s[i] = ga[w_off + o * 90 + k];
    }
    __syncthreads();

    int x = threadIdx.x % 32, yg = threadIdx.x / 32;
    float acc[4][16];
    #pragma unroll
    for (int r = 0; r < 4; ++r)
        #pragma unroll
        for (int o = 0; o < 16; ++o) acc[r][o] = 0.f;

    const uint4* wq = (const uint4*)w_s;
    for (int c = 0; c < 10; ++c) {
        #pragma unroll
        for (int ky = 0; ky < 3; ++ky) {
            #pragma unroll
            for (int kx = 0; kx < 3; ++kx) {
                int k = (c * 3 + ky) * 3 + kx;
                float a[4];
                #pragma unroll
                for (int r = 0; r < 4; ++r)
                    a[r] = us2f(patch[c * 1156 + (yg + 8 * r + ky) * 34 + (x + kx)]);
                uint4 q0 = wq[k * 2], q1 = wq[k * 2 + 1];
                float wv[16];
                wv[0]=ulo(q0.x); wv[1]=uhi(q0.x); wv[2]=ulo(q0.y); wv[3]=uhi(q0.y);
                wv[4]=ulo(q0.z); wv[5]=uhi(q0.z); wv[6]=ulo(q0.w); wv[7]=uhi(q0.w);
                wv[8]=ulo(q1.x); wv[9]=uhi(q1.x); wv[10]=ulo(q1.y); wv[11]=uhi(q1.y);
                wv[12]=ulo(q1.z); wv[13]=uhi(q1.z); wv[14]=ulo(q1.w); wv[15]=uhi(q1.w);
                #pragma unroll
                for (int r = 0; r < 4; ++r)
                    #pragma unroll
                    for (int o = 0; o < 16; ++o)
                        acc[r][o] += a[r] * wv[o];
            }
        }
    }
    #pragma unroll
    for (int o = 0; o < 16; ++o) {
        float b = us2f(ga[b_off + o]);
        float al = us2f(ga[a_off + o]);
        #pragma unroll
        for (int r = 0; r < 4; ++r) {
            int gy = y0 + yg + 8 * r, gx = x0 + x;
            if (gy < 357 && gx < 357) {
                float v = acc[r][o] + b;
                v = v > 0.f ? v : v * al;
                g_arena[(long)out_off + ((long)(n * 16 + o) * 357 + gy) * 357 + gx] = f2b(v);
            }
        }
    }
}

// ---------------------------------------------------------------------------
// PNet conv3 (16->32) + PReLU + heads, conv via MFMA 32x32x16 bf16.
// K-order: k' = (ky*3+kx)*16 + c  (9 groups x 16 channels = 144, 9 MFMA steps).
// patchT[row*34+col][c]: c contiguous -> A fragment = 1 ds_read_b128.
// Pixel stride 24 u16 (48B): b128 gathers spread uniformly over banks.
// w3r[o][k']: k' contiguous -> B fragment = 1 ds_read_b128, preloaded.
// D layout (m74/m101 verified): col(o)=lane&31, row(px)=(reg&3)+8*(reg>>2)+4*(lane>>5).
// Block = (n, 8-row band, 32-col tile); wave w owns rows 2w, 2w+1 (2 m-tiles).
// Epilogue + head phase identical to the round-6 kernel (fp32 c3s[p*33+o]).
// ---------------------------------------------------------------------------
__launch_bounds__(256)
__global__ void pnet_c3h_kern(int in_off, int w3o, int b3o, int a3o,
                              int w41o, int b41o, int w42o, int b42o, void* dout)
{
    constexpr int PST = 24;
    __shared__ __align__(16) u16 patchT[340 * PST];   // 16320 B
    __shared__ __align__(16) u16 w3r[32 * 160];       // 10240 B
    __shared__ float c3s[256 * 33];                   // 33792 B
    __shared__ float b3f[32], a3f[32], w41f[64], w42f[128], b41f[2], b42f[4];

    int n = blockIdx.x, by = blockIdx.y, tx = blockIdx.z;
    int gy0 = by * 8, gx0 = tx * 32;
    const u16* ga = (const u16*)g_arena;

    // stage patchT: [row*34+col][c]
    for (int i = threadIdx.x; i < 5440; i += 256) {
        int c = i / 340, rem = i % 340;
        int py = rem / 34, pxx = rem % 34;
        int iy = gy0 + py, ix = gx0 + pxx;
        u16 v = 0;
        if (iy < 357 && ix < 357)
            v = ga[in_off + ((long)(n * 16 + c) * 357 + iy) * 357 + ix];
        patchT[rem * PST + c] = v;
    }
    // stage w3r[o][g*16+c] = w3[o][c*9+g]
    for (int i = threadIdx.x; i < 5120; i += 256) {
        int o = i / 160, kp = i % 160;
        int g = kp >> 4, c = kp & 15;
        w3r[i] = (g < 9) ? ga[w3o + o * 144 + c * 9 + g] : (u16)0;
    }
    for (int i = threadIdx.x; i < 32; i += 256) { b3f[i] = us2f(ga[b3o + i]); a3f[i] = us2f(ga[a3o + i]); }
    for (int i = threadIdx.x; i < 64; i += 256) w41f[i] = us2f(ga[w41o + i]);
    for (int i = threadIdx.x; i < 128; i += 256) w42f[i] = us2f(ga[w42o + i]);
    if (threadIdx.x < 2) b41f[threadIdx.x] = us2f(ga[b41o + threadIdx.x]);
    if (threadIdx.x < 4) b42f[threadIdx.x] = us2f(ga[b42o + threadIdx.x]);
    __syncthreads();

    int lane = threadIdx.x & 63, w = threadIdx.x >> 6;
    int half = lane >> 5, m = lane & 31;
    int c0 = half * 8;

    // preload B fragments (9 x b128 per lane)
    s16x8 bfrag[9];
    #pragma unroll
    for (int g = 0; g < 9; ++g)
        bfrag[g] = *(const s16x8*)&w3r[m * 160 + g * 16 + c0];

    f32x16 acc0 = {}, acc1 = {};
    #pragma unroll
    for (int g = 0; g < 9; ++g) {
        int ky = g / 3, kx = g % 3;
        s16x8 a0 = *(const s16x8*)&patchT[((2 * w + 0 + ky) * 34 + m + kx) * PST + c0];
        s16x8 a1 = *(const s16x8*)&patchT[((2 * w + 1 + ky) * 34 + m + kx) * PST + c0];
        acc0 = __builtin_amdgcn_mfma_f32_32x32x16_bf16(a0, bfrag[g], acc0, 0, 0, 0);
        acc1 = __builtin_amdgcn_mfma_f32_32x32x16_bf16(a1, bfrag[g], acc1, 0, 0, 0);
    }

    // epilogue: bias + PReLU, scatter to c3s[p*33 + o]
    {
        float b = b3f[m], al = a3f[m];      // o = m = lane&31
        #pragma unroll
        for (int reg = 0; reg < 16; ++reg) {
            int mrow = (reg & 3) + 8 * (reg >> 2) + 4 * half;
            float v0 = acc0[reg] + b; v0 = v0 > 0.f ? v0 : v0 * al;
            c3s[(w * 64 + mrow) * 33 + m] = v0;
            float v1 = acc1[reg] + b; v1 = v1 > 0.f ? v1 : v1 * al;
            c3s[(w * 64 + 32 + mrow) * 33 + m] = v1;
        }
    }
    __syncthreads();

    int p = threadIdx.x;
    int gy = gy0 + (p >> 5), gx = gx0 + (p & 31);
    if (gy < 355 && gx < 355) {
        int f32 = g_isf32;
        float l0 = b41f[0], l1 = b41f[1];
        float r0 = b42f[0], r1 = b42f[1], r2 = b42f[2], r3 = b42f[3];
        #pragma unroll
        for (int o = 0; o < 32; ++o) {
            float v = c3s[p * 33 + o];
            l0 += v * w41f[o];
            l1 += v * w41f[32 + o];
            r0 += v * w42f[o];
            r1 += v * w42f[32 + o];
            r2 += v * w42f[64 + o];
            r3 += v * w42f[96 + o];
        }
        float mx = fmaxf(l0, l1);
        float e0 = __expf(l0 - mx), e1 = __expf(l1 - mx);
        float inv = 1.f / (e0 + e1);
        const long HW = 355L * 355L;
        long pix = (long)gy * 355 + gx;
        stout(dout, 4032800 + ((long)n * 2 + 0) * HW + pix, e0 * inv, f32);
        stout(dout, 4032800 + ((long)n * 2 + 1) * HW + pix, e1 * inv, f32);
        stout(dout, ((long)n * 4 + 0) * HW + pix, r0, f32);
        stout(dout, ((long)n * 4 + 1) * HW + pix, r1, f32);
        stout(dout, ((long)n * 4 + 2) * HW + pix, r2, f32);
        stout(dout, ((long)n * 4 + 3) * HW + pix, r3, f32);
    }
}

// ---------------------------------------------------------------------------
// MaxPool2d, ceil_mode (OOB taps skipped).
// ---------------------------------------------------------------------------
__global__ void maxpool_kern(int in_off, int out_off,
                             int H, int W, int OH, int OW, int k, int s, int total)
{
    int tid = blockIdx.x * blockDim.x + threadIdx.x;
    if (tid >= total) return;
    int x = tid % OW;
    int t = tid / OW;
    int y = t % OH;
    int nc = t / OH;
    const bf16* ip = g_arena + in_off + (long)nc * H * W;
    int sy = y * s, sx = x * s;
    float m = -1e30f;
    for (int ky = 0; ky < k; ++ky) {
        int iy = sy + ky;
        if (iy >= H) break;
        for (int kx = 0; kx < k; ++kx) {
            int ix = sx + kx;
            if (ix >= W) break;
            m = fmaxf(m, b2f(ip[iy * W + ix]));
        }
    }
    g_arena[(long)out_off + tid] = f2b(m);
}

// ---------------------------------------------------------------------------
// Flatten: torch permute(0,3,2,1).view -> out[n][w*H*C + h*C + c]
// ---------------------------------------------------------------------------
__global__ void flatten_kern(int in_off, int out_off, int C, int H, int W, int total)
{
    int tid = blockIdx.x * blockDim.x + threadIdx.x;
    if (tid >= total) return;
    int CHW = C * H * W;
    int n = tid / CHW;
    int k = tid % CHW;
    int w = k / (H * C);
    int r = k % (H * C);
    int h = r / C;
    int c = r % C;
    g_arena[(long)out_off + tid] = g_arena[in_off + (((long)n * C + c) * H + h) * W + w];
}

// ---------------------------------------------------------------------------
// Dense + bias + PReLU as tiled LDS GEMM (32x32 tile, 2x2 micro-tile).
// ---------------------------------------------------------------------------
__launch_bounds__(256)
__global__ void dense_tile_kern(int in_off, int w_off, int b_off, int a_off, int out_off,
                                int K, int J)
{
    __shared__ u16 in_s[32 * 66];
    __shared__ u16 w_s[32 * 66];
    int n0 = blockIdx.x * 32, j0 = blockIdx.y * 32;
    const u16* ga = (const u16*)g_arena;
    const u16* fin = ga + in_off;
    const u16* wts = ga + w_off;
    int sy = threadIdx.x >> 4, sx = threadIdx.x & 15;

    float acc00 = 0.f, acc01 = 0.f, acc10 = 0.f, acc11 = 0.f;

    for (int kc = 0; kc < K; kc += 64) {
        #pragma unroll
        for (int it = 0; it < 4; ++it) {
            int i = threadIdx.x + it * 256;
            int row = i >> 5, c2 = i & 31;
            u32 v = *(const u32*)(fin + (long)(n0 + row) * K + kc + c2 * 2);
            *(u32*)&in_s[row * 66 + c2 * 2] = v;
            u32 wv = *(const u32*)(wts + (long)(j0 + row) * K + kc + c2 * 2);
            *(u32*)&w_s[row * 66 + c2 * 2] = wv;
        }
        __syncthreads();
        #pragma unroll
        for (int kk = 0; kk < 64; ++kk) {
            float a0 = us2f(in_s[(2 * sy) * 66 + kk]);
            float a1 = us2f(in_s[(2 * sy + 1) * 66 + kk]);
            float b0 = us2f(w_s[(2 * sx) * 66 + kk]);
            float b1 = us2f(w_s[(2 * sx + 1) * 66 + kk]);
            acc00 += a0 * b0; acc01 += a0 * b1;
            acc10 += a1 * b0; acc11 += a1 * b1;
        }
        __syncthreads();
    }

    float accs[2][2] = {{acc00, acc01}, {acc10, acc11}};
    #pragma unroll
    for (int jj = 0; jj < 2; ++jj) {
        int j = j0 + 2 * sx + jj;
        float b = us2f(ga[b_off + j]);
        float al = us2f(ga[a_off + j]);
        #pragma unroll
        for (int ss = 0; ss < 2; ++ss) {
            int n = n0 + 2 * sy + ss;
            float v = accs[ss][jj] + b;
            v = v > 0.f ? v : v * al;
            g_arena[(long)out_off + (long)n * J + j] = f2b(v);
        }
    }
}

// ---------------------------------------------------------------------------
// Heads, wave-per-sample: 64 lanes partition K; butterfly shuffle reduction.
// ---------------------------------------------------------------------------
template<int K, int J1, int J2>
__launch_bounds__(256)
__global__ void heads_wave_kern(int fc_off, int wSo, int bSo, int w1o, int b1o,
                                int w2o, int b2o, void* dout,
                                long outS_off, long out1_off, long out2_off, int N)
{
    constexpr int KPL = K / 64;
    constexpr int NACC = 2 + J1 + J2;
    int wave = (blockIdx.x * blockDim.x + threadIdx.x) >> 6;
    int lane = threadIdx.x & 63;
    if (wave >= N) return;
    const u16* ga = (const u16*)g_arena;
    const u16* f  = ga + fc_off + (long)wave * K;
    const u16* wS = ga + wSo;
    const u16* w1 = ga + w1o;
    const u16* w2 = ga + w2o;

    float acc[NACC];
    #pragma unroll
    for (int j = 0; j < NACC; ++j) acc[j] = 0.f;

    #pragma unroll
    for (int kk = 0; kk < KPL; ++kk) {
        int k = lane + kk * 64;
        float fv = us2f(f[k]);
        acc[0] += fv * us2f(wS[k]);
        acc[1] += fv * us2f(wS[K + k]);
        #pragma unroll
        for (int j = 0; j < J1; ++j)
            acc[2 + j] += fv * us2f(w1[j * K + k]);
        #pragma unroll
        for (int j = 0; j < J2; ++j)
            acc[2 + J1 + j] += fv * us2f(w2[j * K + k]);
    }
    #pragma unroll
    for (int j = 0; j < NACC; ++j)
        #pragma unroll
        for (int off = 32; off > 0; off >>= 1)
            acc[j] += __shfl_xor(acc[j], off, 64);

    if (lane == 0) {
        int f32 = g_isf32;
        float l0 = acc[0] + us2f(ga[bSo + 0]);
        float l1 = acc[1] + us2f(ga[bSo + 1]);
        float m = fmaxf(l0, l1);
        float e0 = __expf(l0 - m), e1 = __expf(l1 - m);
        float inv = 1.f / (e0 + e1);
        stout(dout, outS_off + (long)wave * 2 + 0, e0 * inv, f32);
        stout(dout, outS_off + (long)wave * 2 + 1, e1 * inv, f32);
        #pragma unroll
        for (int j = 0; j < J1; ++j)
            stout(dout, out1_off + (long)wave * J1 + j, acc[2 + j] + us2f(ga[b1o + j]), f32);
        #pragma unroll
        for (int j = 0; j < J2; ++j)
            stout(dout, out2_off + (long)wave * J2 + j, acc[2 + J1 + j] + us2f(ga[b2o + j]), f32);
    }
}

static inline dim3 g1(int total) { return dim3((unsigned)((total + 255) / 256)); }

extern "C" void kernel_launch(void* const* d_in, const int* in_sizes, int n_in,
                              void* d_out, int out_size, void* d_ws, size_t ws_size,
                              hipStream_t stream)
{
    int woff[53];
    int acc = OFF_WTS;
    int mx = 0;
    for (int i = 3; i < 53; ++i) { woff[i] = acc; acc += in_sizes[i]; if (in_sizes[i] > mx) mx = in_sizes[i]; }

    detect_kern<<<1, 64, 0, stream>>>(d_in[0]);
    convert_kern<<<g1(12441600), 256, 0, stream>>>(d_in[0], OFF_IMGS, 12441600);
    convert_kern<<<g1(3538944), 256, 0, stream>>>(d_in[1], OFF_C24, 3538944);
    convert_kern<<<g1(3538944), 256, 0, stream>>>(d_in[2], OFF_C48, 3538944);
    CvtTab tab;
    for (int i = 3; i < 53; ++i) tab.e[i - 3] = CvtEnt{ d_in[i], woff[i], in_sizes[i] };
    convert_many_kern<<<dim3((unsigned)((mx + 255) / 256), 50), 256, 0, stream>>>(tab);

    // ================= PNet =================
    pnet_c1p_kern<<<dim3(8, 23, 23), 256, 0, stream>>>(woff[3], woff[4], woff[5], OFF_A);
    pnet_c2_kern<<<dim3(8, 12, 12), 256, 0, stream>>>(OFF_A, woff[6], woff[7], woff[8], OFF_B);
    pnet_c3h_kern<<<dim3(8, 45, 12), 256, 0, stream>>>(OFF_B,
        woff[9], woff[10], woff[11], woff[12], woff[13], woff[14], woff[15], d_out);

    // ================= RNet =================
    conv_a_kern<3,3,3,24,24,22,22,28,32,4><<<dim3(2048, 4, 1), 256, 0, stream>>>(
        OFF_C24, woff[16], woff[17], woff[18], OFF_A);
    maxpool_kern<<<g1(6938624), 256, 0, stream>>>(OFF_A, OFF_B, 22, 22, 11, 11, 3, 2, 6938624);
    conv_a_kern<28,3,3,11,11,9,9,48,48,3><<<dim3(2048, 1, 1), 256, 0, stream>>>(
        OFF_B, woff[19], woff[20], woff[21], OFF_A);
    maxpool_kern<<<g1(1572864), 256, 0, stream>>>(OFF_A, OFF_B, 9, 9, 4, 4, 3, 2, 1572864);
    conv_a_kern<48,2,2,4,4,3,3,64,64,1><<<dim3(2048, 1, 1), 256, 0, stream>>>(
        OFF_B, woff[22], woff[23], woff[24], OFF_A);
    flatten_kern<<<g1(1179648), 256, 0, stream>>>(OFF_A, OFF_B, 64, 3, 3, 1179648);
    dense_tile_kern<<<dim3(64, 4), 256, 0, stream>>>(OFF_B, woff[25], woff[26], woff[27], OFF_A,
        576, 128);
    heads_wave_kern<128,4,0><<<dim3(512), 256, 0, stream>>>(OFF_A,
        woff[28], woff[29], woff[30], woff[31], 0, 0,
        d_out, 6057392L, 6049200L, 0L, 2048);

    // ================= ONet =================
    conv_a_kern<3,3,3,48,48,46,46,32,32,4><<<dim3(512, 17, 1), 256, 0, stream>>>(
        OFF_C48, woff[32], woff[33], woff[34], OFF_A);
    maxpool_kern<<<g1(8667136), 256, 0, stream>>>(OFF_A, OFF_B, 46, 46, 23, 23, 3, 2, 8667136);
    conv_a_kern<32,3,3,23,23,21,21,64,32,4><<<dim3(512, 4, 2), 256, 0, stream>>>(
        OFF_B, woff[35], woff[36], woff[37], OFF_A);
    maxpool_kern<<<g1(3276800), 256, 0, stream>>>(OFF_A, OFF_B, 21, 21, 10, 10, 3, 2, 3276800);
    conv_a_kern<64,3,3,10,10,8,8,64,16,2><<<dim3(512, 1, 4), 256, 0, stream>>>(
        OFF_B, woff[38], woff[39], woff[40], OFF_A);
    maxpool_kern<<<g1(524288), 256, 0, stream>>>(OFF_A, OFF_B, 8, 8, 4, 4, 2, 2, 524288);
    conv_a_kern<64,2,2,4,4,3,3,128,64,1><<<dim3(512, 1, 2), 256, 0, stream>>>(
        OFF_B, woff[41], woff[42], woff[43], OFF_A);
    flatten_kern<<<g1(589824), 256, 0, stream>>>(OFF_A, OFF_B, 128, 3, 3, 589824);
    dense_tile_kern<<<dim3(16, 8), 256, 0, stream>>>(OFF_B, woff[44], woff[45], woff[46], OFF_A,
        1152, 256);
    heads_wave_kern<256,4,10><<<dim3(128), 256, 0, stream>>>(OFF_A,
        woff[47], woff[48], woff[49], woff[50], woff[51], woff[52],
        d_out, 6068656L, 6061488L, 6063536L, 512);
}